// Round 7
// baseline (322.239 us; speedup 1.0000x reference)
//
#include <hip/hip_runtime.h>
#include <cfloat>
#include <cmath>

// Problem: VectorQuantizer. inputs [16,8,512,64] fp32 (N=65536 rows, D=64),
// weight [512,64] fp32 (K=512). Outputs concat fp32:
//   [0] loss | [1..4194304] quantized_st | [4194305] perplexity | [4194306..] encodings (N*K)

#define OFF_LOSS  0
#define OFF_QUANT 1
#define OFF_PERP  4194305
#define OFF_ENC   4194306
#define VQ_EPS  1.1920929e-7f

// ws layout (u32): [0] sse(float) | [16..527] counts | [544..1055] wn (float)
#define WS_CNT 16
#define WS_WN  544

// init + precompute ||w_k||^2 (sequential-d fma order -> bit-identical
// distances downstream; validated absmax 0.0 in rounds 5/6)
__global__ void vq_init(const float* __restrict__ w, unsigned* __restrict__ ws) {
    int t = threadIdx.x;  // 1024
    if (t < 544) ws[t] = 0u;
    if (t < 512) {
        const float4* wr = (const float4*)(w + (t << 6));
        float n = 0.f;
#pragma unroll
        for (int c = 0; c < 16; ++c) {
            float4 v = wr[c];
            n = fmaf(v.x, v.x, n);
            n = fmaf(v.y, v.y, n);
            n = fmaf(v.z, v.z, n);
            n = fmaf(v.w, v.w, n);
        }
        ((float*)ws)[WS_WN + t] = n;
    }
}

__global__ void __launch_bounds__(1024)
__attribute__((amdgpu_waves_per_eu(4, 4)))   // pin 4 waves/EU: LDS caps at 1 block/CU anyway; frees VGPR budget to 128
vq_main(const float* __restrict__ x, const float* __restrict__ w,
        float* __restrict__ out, float* __restrict__ ws)
{
    extern __shared__ float smem[];
    float* wt = smem;   // chunk-major W, float4 view [16][512], code k stored at k^(c&7); 128 KB (only LDS use)

    const int t    = threadIdx.x;
    const int lane = t & 63;
    const int wid_u = __builtin_amdgcn_readfirstlane(t >> 6);  // force wave-uniform row math -> s_load path

    // ---- stage W: coalesced global float4 reads; swizzled LDS writes (2-way max)
    {
        float4* wf4w = (float4*)wt;
        const float4* w4 = (const float4*)w;
#pragma unroll
        for (int i = 0; i < 8; ++i) {
            int e = t + (i << 10);           // float4 index into w [512][16]
            int k = e >> 4;
            int c = e & 15;
            wf4w[(c << 9) + (k ^ (c & 7))] = w4[e];
        }
    }

    // ---- per-lane ||w_k||^2 for codes k=j*64+lane (precomputed by vq_init)
    const float* wsf = (const float*)ws;
    float wn[8];
#pragma unroll
    for (int j = 0; j < 8; ++j) wn[j] = wsf[WS_WN + (j << 6) + lane];

    __syncthreads();

    float sse = 0.f;
    const int waveRow0 = (blockIdx.x << 8) + (wid_u << 4);  // 256 rows/block, 16/wave
    const float4* wf4 = (const float4*)wt;

    for (int iter = 0; iter < 2; ++iter) {
        const int row0 = waveRow0 + (iter << 3);
        const float4* xb = (const float4*)x + ((size_t)row0 << 4);  // uniform base

        // ---- ||x_row||^2: same octet+tree order as the validated shfl version
        //      (so[o] = seq sum of x[8o..8o+7]; tree ((0+1)+(2+3))+((4+5)+(6+7)))
        float xn_s[8];
#pragma unroll
        for (int r = 0; r < 8; ++r) {
            const float4* p = xb + (r << 4);
            float so[8];
#pragma unroll
            for (int o = 0; o < 8; ++o) {
                float4 a = p[o * 2];
                float4 b = p[o * 2 + 1];
                so[o] = a.x*a.x + a.y*a.y + a.z*a.z + a.w*a.w
                      + b.x*b.x + b.y*b.y + b.z*b.z + b.w*b.w;
            }
            xn_s[r] = ((so[0] + so[1]) + (so[2] + so[3]))
                    + ((so[4] + so[5]) + (so[6] + so[7]));
        }

        // ---- s[r][j] = x_row . w_code(j*64+lane); x via SGPR (scalar loads),
        //      W via swizzled LDS b128; strict d-ascending fma (bit-exact)
        float s[8][8];
#pragma unroll
        for (int r = 0; r < 8; ++r)
#pragma unroll
            for (int j = 0; j < 8; ++j) s[r][j] = 0.f;

#pragma unroll 4
        for (int c = 0; c < 16; ++c) {
            float4 xc[8];
#pragma unroll
            for (int r = 0; r < 8; ++r) xc[r] = xb[(r << 4) + c];   // s_load_dwordx4
            const int lbase = (c << 9) + (lane ^ (c & 7));
#pragma unroll
            for (int jh = 0; jh < 2; ++jh) {
                float4 wq4[4];
#pragma unroll
                for (int jj = 0; jj < 4; ++jj)
                    wq4[jj] = wf4[lbase + (((jh << 2) + jj) << 6)];
#pragma unroll
                for (int r = 0; r < 8; ++r) {
#pragma unroll
                    for (int jj = 0; jj < 4; ++jj) {
                        float acc = s[r][(jh << 2) + jj];
                        acc = fmaf(xc[r].x, wq4[jj].x, acc);
                        acc = fmaf(xc[r].y, wq4[jj].y, acc);
                        acc = fmaf(xc[r].z, wq4[jj].z, acc);
                        acc = fmaf(xc[r].w, wq4[jj].w, acc);
                        s[r][(jh << 2) + jj] = acc;
                    }
                }
            }
        }

        // ---- argmin per row (identical formula + tie-break: j ascending, then
        //      butterfly with index tie-break)
        int bk_arr[8];
#pragma unroll
        for (int r = 0; r < 8; ++r) {
            float xn = xn_s[r];
            float bv = FLT_MAX;
            int   bk = 0;
#pragma unroll
            for (int j = 0; j < 8; ++j) {
                float dv = (xn + wn[j]) - 2.0f * s[r][j];
                if (dv < bv) { bv = dv; bk = (j << 6) + lane; }
            }
#pragma unroll
            for (int off = 1; off < 64; off <<= 1) {
                float ov = __shfl_xor(bv, off);
                int   ok = __shfl_xor(bk, off);
                if (ov < bv || (ov == bv && ok < bk)) { bv = ov; bk = ok; }
            }
            bk_arr[r] = bk;
        }

        // ---- gather codebook rows (L2-resident)
        float wq[8];
#pragma unroll
        for (int r = 0; r < 8; ++r) wq[r] = w[((size_t)bk_arr[r] << 6) + lane];

        // ---- outputs: quantized_st, sse, one-hot (2x float4), histogram
#pragma unroll
        for (int r = 0; r < 8; ++r) {
            const int row = row0 + r;
            float xval = x[((size_t)row << 6) + lane];   // coalesced, L2-hot
            float q    = wq[r];
            out[OFF_QUANT + ((size_t)row << 6) + lane] = xval + (q - xval);
            float df = q - xval;
            sse = fmaf(df, df, sse);

            int kk = bk_arr[r];
            int b  = lane << 3;
            float4 z0, z1;
            z0.x = (kk == b + 0) ? 1.f : 0.f;
            z0.y = (kk == b + 1) ? 1.f : 0.f;
            z0.z = (kk == b + 2) ? 1.f : 0.f;
            z0.w = (kk == b + 3) ? 1.f : 0.f;
            z1.x = (kk == b + 4) ? 1.f : 0.f;
            z1.y = (kk == b + 5) ? 1.f : 0.f;
            z1.z = (kk == b + 6) ? 1.f : 0.f;
            z1.w = (kk == b + 7) ? 1.f : 0.f;
            float4* ebase = (float4*)(out + OFF_ENC + ((size_t)row << 9) + (lane << 3));
            ebase[0] = z0;
            ebase[1] = z1;
            if (lane == r) atomicAdd(((unsigned*)ws) + WS_CNT + kk, 1u);
        }
    }

    // ---- loss partial
#pragma unroll
    for (int off = 1; off < 64; off <<= 1) sse += __shfl_xor(sse, off);
    if (lane == 0) atomicAdd((float*)ws, sse);
}

__global__ void vq_fin(const unsigned* __restrict__ ws, float* __restrict__ out)
{
    __shared__ float red[8];
    int t = threadIdx.x;   // 512 threads
    unsigned c = ws[WS_CNT + t];
    float p = (float)c * (1.0f / 65536.0f);
    float v = p * logf(p + VQ_EPS);
#pragma unroll
    for (int off = 1; off < 64; off <<= 1) v += __shfl_xor(v, off);
    if ((t & 63) == 0) red[t >> 6] = v;
    __syncthreads();
    if (t == 0) {
        float s2 = 0.f;
#pragma unroll
        for (int i = 0; i < 8; ++i) s2 += red[i];
        out[OFF_PERP] = expf(-s2);
        float sse = ((const float*)ws)[0];
        float m = sse * (1.0f / 4194304.0f);
        out[OFF_LOSS] = m + 0.25f * m;
    }
}

extern "C" void kernel_launch(void* const* d_in, const int* in_sizes, int n_in,
                              void* d_out, int out_size, void* d_ws, size_t ws_size,
                              hipStream_t stream) {
    const float* x = (const float*)d_in[0];
    const float* w = (const float*)d_in[1];
    float* out = (float*)d_out;
    unsigned* ws = (unsigned*)d_ws;

    const size_t smem = (size_t)(64 * 512) * 4;  // 128 KiB: W only (x no longer staged)
    (void)hipFuncSetAttribute((const void*)vq_main,
                              hipFuncAttributeMaxDynamicSharedMemorySize, (int)smem);

    hipLaunchKernelGGL(vq_init, dim3(1), dim3(1024), 0, stream, w, ws);
    hipLaunchKernelGGL(vq_main, dim3(256), dim3(1024), smem, stream, x, w, out, (float*)ws);
    hipLaunchKernelGGL(vq_fin,  dim3(1), dim3(512), 0, stream, ws, out);
}

// Round 8
// 261.666 us; speedup vs baseline: 1.2315x; 1.2315x over previous
//
#include <hip/hip_runtime.h>
#include <cfloat>
#include <cmath>

// Problem: VectorQuantizer. inputs [16,8,512,64] fp32 (N=65536 rows, D=64),
// weight [512,64] fp32 (K=512). Outputs concat fp32:
//   [0] loss | [1..4194304] quantized_st | [4194305] perplexity | [4194306..] encodings (N*K)
// NOTE: OFF_ENC*4 mod 16 == 8 -> float4 stores to encodings are misaligned
// (write amplification 232MB vs 148MB measured r6 vs r1). Use float2 (8B-aligned).

#define OFF_LOSS  0
#define OFF_QUANT 1
#define OFF_PERP  4194305
#define OFF_ENC   4194306
#define VQ_EPS  1.1920929e-7f

// ws layout (u32): [0] sse(float) | [16..527] counts | [544..1055] wn (float)
#define WS_CNT 16
#define WS_WN  544

__global__ void vq_init(const float* __restrict__ w, unsigned* __restrict__ ws) {
    int t = threadIdx.x;  // 1024
    if (t < 544) ws[t] = 0u;
    if (t < 512) {
        const float4* wr = (const float4*)(w + (t << 6));
        float n = 0.f;
#pragma unroll
        for (int c = 0; c < 16; ++c) {
            float4 v = wr[c];
            n = fmaf(v.x, v.x, n);
            n = fmaf(v.y, v.y, n);
            n = fmaf(v.z, v.z, n);
            n = fmaf(v.w, v.w, n);
        }
        ((float*)ws)[WS_WN + t] = n;
    }
}

__global__ void
__attribute__((amdgpu_flat_work_group_size(1024, 1024), amdgpu_waves_per_eu(4, 4)))
vq_main(const float* __restrict__ x, const float* __restrict__ w,
        float* __restrict__ out, float* __restrict__ ws)
{
    extern __shared__ float smem[];
    float* wt   = smem;            // chunk-major W, float4 view [16][512], code k stored at k^(c&7); 128 KB
    float* xlds = smem + 64 * 512; // [16 waves][8 rows][64], 32 KB

    const int t    = threadIdx.x;
    const int lane = t & 63;
    const int wid  = t >> 6;
    const float* wsf = (const float*)ws;

    // ---- stage W: coalesced global float4 reads; swizzled LDS writes (2-way max)
    {
        float4* wf4w = (float4*)wt;
        const float4* w4 = (const float4*)w;
#pragma unroll
        for (int i = 0; i < 8; ++i) {
            int e = t + (i << 10);           // float4 index into w [512][16]
            int k = e >> 4;
            int c = e & 15;
            wf4w[(c << 9) + (k ^ (c & 7))] = w4[e];
        }
    }

    // ---- per-lane ||w_k||^2 for codes k=j*64+lane (precomputed by vq_init)
    float wn[8];
#pragma unroll
    for (int j = 0; j < 8; ++j) wn[j] = wsf[WS_WN + (j << 6) + lane];

    __syncthreads();

    float sse = 0.f;
    const int waveRow0 = (blockIdx.x << 8) + (wid << 4);  // 256 rows/block, 16/wave
    float* myx = xlds + (wid << 9);                       // [8][64]
    const float4* wf4 = (const float4*)wt;
    const float4* xf4 = (const float4*)myx;

    for (int iter = 0; iter < 2; ++iter) {
        const int row0 = waveRow0 + (iter << 3);

        // ---- stage 8 rows of x (wave-private; DS ops in-order within wave)
        float xn_bc;
        {
            const float* src = x + ((size_t)row0 << 6) + (lane << 3);
            float4 a = *(const float4*)src;
            float4 b = *(const float4*)(src + 4);
            int r  = lane >> 3;
            int d0 = (lane & 7) << 3;
            *(float4*)(myx + (r << 6) + d0)     = a;
            *(float4*)(myx + (r << 6) + d0 + 4) = b;
            float pn = a.x*a.x + a.y*a.y + a.z*a.z + a.w*a.w
                     + b.x*b.x + b.y*b.y + b.z*b.z + b.w*b.w;
            pn += __shfl_xor(pn, 1);
            pn += __shfl_xor(pn, 2);
            pn += __shfl_xor(pn, 4);
            xn_bc = pn;  // lanes r*8..r*8+7 hold ||x_row(r)||^2
        }

        // ---- distances, j-blocked (4 codes/lane per half), running argmin
        //      fold between halves (j ascending == k ascending per lane)
        float bv[8]; int bk[8];
#pragma unroll
        for (int r = 0; r < 8; ++r) { bv[r] = FLT_MAX; bk[r] = 0; }

#pragma unroll
        for (int jh = 0; jh < 2; ++jh) {
            float s[8][4];
#pragma unroll
            for (int r = 0; r < 8; ++r)
#pragma unroll
                for (int jj = 0; jj < 4; ++jj) s[r][jj] = 0.f;

#pragma unroll 2
            for (int c = 0; c < 16; ++c) {
                const int lofs = (c << 9) + (jh << 8) + (lane ^ (c & 7));
                float4 wq4[4];
#pragma unroll
                for (int jj = 0; jj < 4; ++jj) wq4[jj] = wf4[lofs + (jj << 6)];
#pragma unroll
                for (int r = 0; r < 8; ++r) {
                    float4 xq = xf4[(r << 4) + c];   // LDS broadcast read
#pragma unroll
                    for (int jj = 0; jj < 4; ++jj) {
                        // strict d-ascending accumulation (bit-exact)
                        s[r][jj] = fmaf(xq.x, wq4[jj].x, s[r][jj]);
                        s[r][jj] = fmaf(xq.y, wq4[jj].y, s[r][jj]);
                        s[r][jj] = fmaf(xq.z, wq4[jj].z, s[r][jj]);
                        s[r][jj] = fmaf(xq.w, wq4[jj].w, s[r][jj]);
                    }
                }
            }

#pragma unroll
            for (int r = 0; r < 8; ++r) {
                float xn = __shfl(xn_bc, r << 3);
#pragma unroll
                for (int jj = 0; jj < 4; ++jj) {
                    const int j = (jh << 2) + jj;
                    float dv = (xn + wn[j]) - 2.0f * s[r][jj];
                    if (dv < bv[r]) { bv[r] = dv; bk[r] = (j << 6) + lane; }
                }
            }
        }

        // ---- cross-lane argmin butterfly (identical tie-break)
        int bk_arr[8];
#pragma unroll
        for (int r = 0; r < 8; ++r) {
            float v = bv[r]; int k = bk[r];
#pragma unroll
            for (int off = 1; off < 64; off <<= 1) {
                float ov = __shfl_xor(v, off);
                int   ok = __shfl_xor(k, off);
                if (ov < v || (ov == v && ok < k)) { v = ov; k = ok; }
            }
            bk_arr[r] = k;
        }

        // ---- gather codebook rows (L2-resident)
        float wq[8];
#pragma unroll
        for (int r = 0; r < 8; ++r) wq[r] = w[((size_t)bk_arr[r] << 6) + lane];

        // ---- outputs: quantized_st (b32), sse, one-hot as 4x float2 (8B-aligned),
        //      histogram
#pragma unroll
        for (int r = 0; r < 8; ++r) {
            const int row = row0 + r;
            float xval = myx[(r << 6) + lane];   // LDS, not global (saves fetch)
            float q    = wq[r];
            out[OFF_QUANT + ((size_t)row << 6) + lane] = xval + (q - xval);
            float df = q - xval;
            sse = fmaf(df, df, sse);

            int kk = bk_arr[r];
            int b  = lane << 3;
            float2* ebase = (float2*)(out + OFF_ENC + ((size_t)row << 9) + (lane << 3));
#pragma unroll
            for (int m = 0; m < 4; ++m) {
                float2 f;
                f.x = (kk == b + 2 * m)     ? 1.f : 0.f;
                f.y = (kk == b + 2 * m + 1) ? 1.f : 0.f;
                ebase[m] = f;
            }
            if (lane == r) atomicAdd(((unsigned*)ws) + WS_CNT + kk, 1u);
        }
    }

    // ---- loss partial
#pragma unroll
    for (int off = 1; off < 64; off <<= 1) sse += __shfl_xor(sse, off);
    if (lane == 0) atomicAdd((float*)ws, sse);
}

__global__ void vq_fin(const unsigned* __restrict__ ws, float* __restrict__ out)
{
    __shared__ float red[8];
    int t = threadIdx.x;   // 512 threads
    unsigned c = ws[WS_CNT + t];
    float p = (float)c * (1.0f / 65536.0f);
    float v = p * logf(p + VQ_EPS);
#pragma unroll
    for (int off = 1; off < 64; off <<= 1) v += __shfl_xor(v, off);
    if ((t & 63) == 0) red[t >> 6] = v;
    __syncthreads();
    if (t == 0) {
        float s2 = 0.f;
#pragma unroll
        for (int i = 0; i < 8; ++i) s2 += red[i];
        out[OFF_PERP] = expf(-s2);
        float sse = ((const float*)ws)[0];
        float m = sse * (1.0f / 4194304.0f);
        out[OFF_LOSS] = m + 0.25f * m;
    }
}

extern "C" void kernel_launch(void* const* d_in, const int* in_sizes, int n_in,
                              void* d_out, int out_size, void* d_ws, size_t ws_size,
                              hipStream_t stream) {
    const float* x = (const float*)d_in[0];
    const float* w = (const float*)d_in[1];
    float* out = (float*)d_out;
    unsigned* ws = (unsigned*)d_ws;

    const size_t smem = (size_t)(64 * 512 + 16 * 8 * 64) * 4;  // 160 KiB exactly
    (void)hipFuncSetAttribute((const void*)vq_main,
                              hipFuncAttributeMaxDynamicSharedMemorySize, (int)smem);

    hipLaunchKernelGGL(vq_init, dim3(1), dim3(1024), 0, stream, w, ws);
    hipLaunchKernelGGL(vq_main, dim3(256), dim3(1024), smem, stream, x, w, out, (float*)ws);
    hipLaunchKernelGGL(vq_fin,  dim3(1), dim3(512), 0, stream, ws, out);
}

// Round 10
// 232.276 us; speedup vs baseline: 1.3873x; 1.1265x over previous
//
#include <hip/hip_runtime.h>
#include <cfloat>
#include <cmath>

// Problem: VectorQuantizer. inputs [16,8,512,64] fp32 (N=65536 rows, D=64),
// weight [512,64] fp32 (K=512). Outputs concat fp32:
//   [0] loss | [1..4194304] quantized_st | [4194305] perplexity | [4194306..] encodings (N*K)
//
// Lessons encoded here:
//  - 1024-thread blocks get pinned at 64 arch VGPRs by the toolchain -> use 512
//    threads + __launch_bounds__(512,2) to unlock a 256-VGPR budget so the full
//    8x8 accumulator block lives in registers (no AGPR shuttling).
//  - encodings stores must be per-instruction DENSE: ebase[(m<<6)+lane] covers a
//    contiguous 512B per store instr. Strided (lane<<3 base + m) leaves 8B/32B
//    sectors dirty -> L2 partial-line RMW (+60MB fetch AND write, measured r8).
//  - W in LDS chunk-major float4 [16][512] with k^(c&7) swizzle: staging writes
//    and reads both <=2-way conflict (131K total, measured r6/r8).

#define OFF_LOSS  0
#define OFF_QUANT 1
#define OFF_PERP  4194305
#define OFF_ENC   4194306
#define VQ_EPS  1.1920929e-7f

// ws layout (u32): [0] sse(float) | [16..527] counts | [544..1055] wn (float)
#define WS_CNT 16
#define WS_WN  544

__global__ void vq_init(const float* __restrict__ w, unsigned* __restrict__ ws) {
    int t = threadIdx.x;  // 1024
    if (t < 544) ws[t] = 0u;
    if (t < 512) {
        const float4* wr = (const float4*)(w + (t << 6));
        float n = 0.f;
#pragma unroll
        for (int c = 0; c < 16; ++c) {
            float4 v = wr[c];
            n = fmaf(v.x, v.x, n);
            n = fmaf(v.y, v.y, n);
            n = fmaf(v.z, v.z, n);
            n = fmaf(v.w, v.w, n);
        }
        ((float*)ws)[WS_WN + t] = n;
    }
}

__global__ void __launch_bounds__(512, 2)
vq_main(const float* __restrict__ x, const float* __restrict__ w,
        float* __restrict__ out, float* __restrict__ ws)
{
    extern __shared__ float smem[];
    float* wt   = smem;            // chunk-major W, float4 view [16][512], code k at k^(c&7); 128 KB
    float* xlds = smem + 64 * 512; // [8 waves][8 rows][64], 16 KB

    const int t    = threadIdx.x;
    const int lane = t & 63;
    const int wid  = t >> 6;
    const float* wsf = (const float*)ws;

    // ---- stage W: coalesced global float4 reads; swizzled LDS writes
    {
        float4* wf4w = (float4*)wt;
        const float4* w4 = (const float4*)w;
#pragma unroll
        for (int i = 0; i < 16; ++i) {
            int e = t + (i << 9);            // float4 index into w [512][16]
            int k = e >> 4;
            int c = e & 15;
            wf4w[(c << 9) + (k ^ (c & 7))] = w4[e];
        }
    }

    // ---- per-lane ||w_k||^2 for codes k=j*64+lane (precomputed by vq_init)
    float wn[8];
#pragma unroll
    for (int j = 0; j < 8; ++j) wn[j] = wsf[WS_WN + (j << 6) + lane];

    __syncthreads();

    float sse = 0.f;
    const int waveRow0 = (blockIdx.x << 8) + (wid << 5);  // 256 rows/block, 32/wave
    float* myx = xlds + (wid << 9);                       // [8][64]
    const float4* wf4 = (const float4*)wt;
    const float4* xf4 = (const float4*)myx;

    for (int iter = 0; iter < 4; ++iter) {
        const int row0 = waveRow0 + (iter << 3);

        // ---- stage 8 rows of x (wave-private; DS ops in-order within wave)
        float xn_bc;
        {
            const float* src = x + ((size_t)row0 << 6) + (lane << 3);
            float4 a = *(const float4*)src;
            float4 b = *(const float4*)(src + 4);
            int r  = lane >> 3;
            int d0 = (lane & 7) << 3;
            *(float4*)(myx + (r << 6) + d0)     = a;
            *(float4*)(myx + (r << 6) + d0 + 4) = b;
            float pn = a.x*a.x + a.y*a.y + a.z*a.z + a.w*a.w
                     + b.x*b.x + b.y*b.y + b.z*b.z + b.w*b.w;
            pn += __shfl_xor(pn, 1);
            pn += __shfl_xor(pn, 2);
            pn += __shfl_xor(pn, 4);
            xn_bc = pn;  // lanes r*8..r*8+7 hold ||x_row(r)||^2
        }

        // ---- s[r][j] = x_row(row0+r) . w_code(j*64+lane)
        //      full 8x8 accumulator block; x read ONCE per (c,r) from LDS
        float s[8][8];
#pragma unroll
        for (int r = 0; r < 8; ++r)
#pragma unroll
            for (int j = 0; j < 8; ++j) s[r][j] = 0.f;

#pragma unroll 2
        for (int c = 0; c < 16; ++c) {
            float4 xq[8];
#pragma unroll
            for (int r = 0; r < 8; ++r) xq[r] = xf4[(r << 4) + c];  // broadcast
            const int lbase = (c << 9) + (lane ^ (c & 7));
#pragma unroll
            for (int jh = 0; jh < 2; ++jh) {
                float4 wq4[4];
#pragma unroll
                for (int jj = 0; jj < 4; ++jj)
                    wq4[jj] = wf4[lbase + (((jh << 2) + jj) << 6)];
#pragma unroll
                for (int r = 0; r < 8; ++r) {
#pragma unroll
                    for (int jj = 0; jj < 4; ++jj) {
                        float acc = s[r][(jh << 2) + jj];
                        // strict d-ascending accumulation (bit-exact)
                        acc = fmaf(xq[r].x, wq4[jj].x, acc);
                        acc = fmaf(xq[r].y, wq4[jj].y, acc);
                        acc = fmaf(xq[r].z, wq4[jj].z, acc);
                        acc = fmaf(xq[r].w, wq4[jj].w, acc);
                        s[r][(jh << 2) + jj] = acc;
                    }
                }
            }
        }

        // ---- argmin per row (identical formula + tie-break, validated r4)
        int bk_arr[8];
#pragma unroll
        for (int r = 0; r < 8; ++r) {
            float xn = __shfl(xn_bc, r << 3);
            float bv = FLT_MAX;
            int   bk = 0;
#pragma unroll
            for (int j = 0; j < 8; ++j) {
                float dv = (xn + wn[j]) - 2.0f * s[r][j];
                if (dv < bv) { bv = dv; bk = (j << 6) + lane; }
            }
#pragma unroll
            for (int off = 1; off < 64; off <<= 1) {
                float ov = __shfl_xor(bv, off);
                int   ok = __shfl_xor(bk, off);
                if (ov < bv || (ov == bv && ok < bk)) { bv = ov; bk = ok; }
            }
            bk_arr[r] = bk;
        }

        // ---- gather codebook rows (L2-resident)
        float wq[8];
#pragma unroll
        for (int r = 0; r < 8; ++r) wq[r] = w[((size_t)bk_arr[r] << 6) + lane];

        // ---- outputs: quantized_st, sse, one-hot (dense contiguous float2
        //      stores: each instr covers 512B fully), histogram
#pragma unroll
        for (int r = 0; r < 8; ++r) {
            const int row = row0 + r;
            float xval = myx[(r << 6) + lane];
            float q    = wq[r];
            out[OFF_QUANT + ((size_t)row << 6) + lane] = xval + (q - xval);
            float df = q - xval;
            sse = fmaf(df, df, sse);

            int kk = bk_arr[r];
            float2* ebase = (float2*)(out + OFF_ENC + ((size_t)row << 9));
#pragma unroll
            for (int m = 0; m < 4; ++m) {
                int b = (m << 7) + (lane << 1);
                float2 f;
                f.x = (kk == b)     ? 1.f : 0.f;
                f.y = (kk == b + 1) ? 1.f : 0.f;
                ebase[(m << 6) + lane] = f;   // contiguous 512B per instruction
            }
            if (lane == r) atomicAdd(((unsigned*)ws) + WS_CNT + kk, 1u);
        }
    }

    // ---- loss partial
#pragma unroll
    for (int off = 1; off < 64; off <<= 1) sse += __shfl_xor(sse, off);
    if (lane == 0) atomicAdd((float*)ws, sse);
}

__global__ void vq_fin(const unsigned* __restrict__ ws, float* __restrict__ out)
{
    __shared__ float red[8];
    int t = threadIdx.x;   // 512 threads
    unsigned c = ws[WS_CNT + t];
    float p = (float)c * (1.0f / 65536.0f);
    float v = p * logf(p + VQ_EPS);
#pragma unroll
    for (int off = 1; off < 64; off <<= 1) v += __shfl_xor(v, off);
    if ((t & 63) == 0) red[t >> 6] = v;
    __syncthreads();
    if (t == 0) {
        float s2 = 0.f;
#pragma unroll
        for (int i = 0; i < 8; ++i) s2 += red[i];
        out[OFF_PERP] = expf(-s2);
        float sse = ((const float*)ws)[0];
        float m = sse * (1.0f / 4194304.0f);
        out[OFF_LOSS] = m + 0.25f * m;
    }
}

extern "C" void kernel_launch(void* const* d_in, const int* in_sizes, int n_in,
                              void* d_out, int out_size, void* d_ws, size_t ws_size,
                              hipStream_t stream) {
    const float* x = (const float*)d_in[0];
    const float* w = (const float*)d_in[1];
    float* out = (float*)d_out;
    unsigned* ws = (unsigned*)d_ws;

    const size_t smem = (size_t)(64 * 512 + 8 * 8 * 64) * 4;  // 144 KiB
    (void)hipFuncSetAttribute((const void*)vq_main,
                              hipFuncAttributeMaxDynamicSharedMemorySize, (int)smem);

    hipLaunchKernelGGL(vq_init, dim3(1), dim3(1024), 0, stream, w, ws);
    hipLaunchKernelGGL(vq_main, dim3(256), dim3(512), smem, stream, x, w, out, (float*)ws);
    hipLaunchKernelGGL(vq_fin,  dim3(1), dim3(512), 0, stream, ws, out);
}